// Round 10
// baseline (433.307 us; speedup 1.0000x reference)
//
#include <hip/hip_runtime.h>
#include <math.h>

#define DD 16
#define HH 64
#define WW 64
#define VV (DD*HH*WW)      // 65536
#define CC 64
#define NHEADS 4
#define NSAMP 8
#define HDIM 16

typedef unsigned int uint;
typedef unsigned short ushort;
typedef __attribute__((ext_vector_type(8))) short bf16x8;
typedef __attribute__((ext_vector_type(4))) float f32x4;

__device__ __forceinline__ float clampf(float v, float lo, float hi){ return fminf(fmaxf(v, lo), hi); }
__device__ __forceinline__ int imin(int a, int b){ return a < b ? a : b; }

// bf16 helpers (RNE)
__device__ __forceinline__ ushort f2bf(float f){
  uint u = __float_as_uint(f);
  uint r = (u + 0x7fffu + ((u>>16)&1u)) >> 16;
  return (ushort)r;
}
__device__ __forceinline__ uint packbf2(float a, float b){
  return (uint)f2bf(a) | ((uint)f2bf(b) << 16);
}
__device__ __forceinline__ float bflo(uint u){ return __uint_as_float(u << 16); }
__device__ __forceinline__ float bfhi(uint u){ return __uint_as_float(u & 0xffff0000u); }
__device__ __forceinline__ float bf2f(ushort u){ return __uint_as_float((uint)u << 16); }

__device__ __forceinline__ float fast_tanh(float x){
  float e = __expf(2.f*x);
  return 1.f - 2.f/(e + 1.f);
}

// ---- inline 1x1 A-fragment from raw fp32 [co][64ci] weights --------------
__device__ __forceinline__ bf16x8 make_af(const float* __restrict__ w, int mt, int ks, int lane){
  const float* p = w + (size_t)(mt*16 + (lane&15))*CC + ks*32 + ((lane>>4)<<3);
  float4 f0 = *reinterpret_cast<const float4*>(p);
  float4 f1 = *reinterpret_cast<const float4*>(p+4);
  union { uint4 u; bf16x8 b; } r;
  r.u.x = packbf2(f0.x, f0.y); r.u.y = packbf2(f0.z, f0.w);
  r.u.z = packbf2(f1.x, f1.y); r.u.w = packbf2(f1.z, f1.w);
  return r.b;
}

// ---- weight repack bodies ------------------------------------------------
__device__ __forceinline__ void repack_wmfma_body(const float* __restrict__ w,
                                                  uint* __restrict__ o, int MG, int U){
  int j2 = U & 3;
  int m  = (U>>2) & 15;
  int q  = (U>>6) & 3;
  int rest = U >> 8;          // s*MG + g
  int g = rest % MG;
  int s = rest / MG;
  int tap = s >> 1, h = s & 1;
  int co = g*16 + m;
  int ci = h*32 + q*8 + j2*2;
  int base = co*1728 + ci*27 + tap;
  o[U] = packbf2(w[base], w[base + 27]);
}
__device__ __forceinline__ void repack_w1_body(const float* __restrict__ w,
                                               uint* __restrict__ o, int MT, int U){
  int j2 = U & 3;
  int lane = (U>>2) & 63;
  int frag = U >> 8;
  int mt = frag % MT;
  int ks = frag / MT;
  int q = lane >> 4, m = lane & 15;
  int co = mt*16 + m;
  int ci = ks*32 + q*8 + j2*2;
  o[U] = packbf2(w[co*CC + ci], w[co*CC + ci + 1]);
}

// ---- 1x1 conv body (MFMA), raw weights, LDS passed in --------------------
// EPI 0: fp32 input (mid); +bias -> vols[head][y][x][z][32ch]; copies mid->mcopy.
// EPI 1: fp32 input (occ/prev by call); also emits the oct-packed input tile
//        to o0out (folds the pack pass); (acc+bias)*0.25 -> q [call][vox][64ch]
template<int CO, int EPI>
__device__ void conv1_body(
    int bid, int tid, ushort* __restrict__ xt,
    const float* __restrict__ xa, const float* __restrict__ xb,
    const float* __restrict__ wraw, const float* __restrict__ bias,
    void* __restrict__ outp, float* __restrict__ mcopy,
    uint* __restrict__ o0out)
{
  constexpr int MT = CO/16;
  constexpr int MW = MT/4;
  int lane = tid & 63;
  int g = __builtin_amdgcn_readfirstlane(tid >> 6);
  int q = lane >> 4, n = lane & 15;
  int call = bid >> 10;
  int v0 = (bid & 1023) * 64;
  bf16x8 afr[2][MW];
  #pragma unroll
  for (int ks=0; ks<2; ks++)
    #pragma unroll
    for (int mw=0; mw<MW; mw++)
      afr[ks][mw] = make_af(wraw, g*MW+mw, ks, lane);
  const float* x = call ? xb : xa;
  for (int it = tid; it < 64*32; it += 256){
    int vox = it & 63; int cp = it >> 6;
    float a = x[(size_t)(2*cp)*VV + v0 + vox];
    float b = x[(size_t)(2*cp+1)*VV + v0 + vox];
    if constexpr (EPI == 0){
      mcopy[(size_t)(2*cp)*VV + v0 + vox] = a;
      mcopy[(size_t)(2*cp+1)*VV + v0 + vox] = b;
    }
    *reinterpret_cast<uint*>(&xt[vox*72 + 2*cp]) = packbf2(a,b);
  }
  __syncthreads();
  if constexpr (EPI == 1){
    // LDS row = 32 consecutive dwords = exactly the oct layout for this voxel.
    uint4* ob = reinterpret_cast<uint4*>(o0out) + (size_t)call*8*VV + v0;
    #pragma unroll
    for (int k=0; k<2; k++){
      int it = tid + k*256;    // 512 items: vox 64 x cg 8
      int vox = it & 63; int cg = it >> 6;
      ob[(size_t)cg*VV + vox] = *reinterpret_cast<const uint4*>(
          reinterpret_cast<const char*>(xt) + vox*144 + cg*16);
    }
  }
  f32x4 acc[MW][4];
  #pragma unroll
  for (int mw=0;mw<MW;mw++)
    #pragma unroll
    for (int nt=0;nt<4;nt++){ acc[mw][nt].x=0.f; acc[mw][nt].y=0.f; acc[mw][nt].z=0.f; acc[mw][nt].w=0.f; }
  const char* ldsb = reinterpret_cast<const char*>(xt);
  #pragma unroll
  for (int ks=0; ks<2; ks++){
    bf16x8 bfr[4];
    #pragma unroll
    for (int nt=0; nt<4; nt++)
      bfr[nt] = *reinterpret_cast<const bf16x8*>(ldsb + ((nt*16+n)*144 + q*16 + ks*64));
    #pragma unroll
    for (int mw=0; mw<MW; mw++)
      #pragma unroll
      for (int nt=0; nt<4; nt++)
        acc[mw][nt] = __builtin_amdgcn_mfma_f32_16x16x32_bf16(afr[ks][mw], bfr[nt], acc[mw][nt], 0, 0, 0);
  }
  if constexpr (EPI == 0){
    #pragma unroll
    for (int mw=0; mw<MW; mw++){
      int mt = g*MW + mw;
      int cob = mt*16 + q*4;
      #pragma unroll
      for (int nt=0; nt<4; nt++){
        int v = v0 + nt*16 + n;
        float r0 = acc[mw][nt].x + bias[cob+0];
        float r1 = acc[mw][nt].y + bias[cob+1];
        float r2 = acc[mw][nt].z + bias[cob+2];
        float r3 = acc[mw][nt].w + bias[cob+3];
        int z = v >> 12, y = (v >> 6) & 63, xx = v & 63;
        int head = cob >> 5;
        uint* vols = (uint*)outp;
        uint2 pk; pk.x = packbf2(r0,r1); pk.y = packbf2(r2,r3);
        *reinterpret_cast<uint2*>(vols + ((size_t)head*VV + (size_t)(y*WW+xx)*DD + z)*16 + ((cob&31)>>1)) = pk;
      }
    }
  } else {
    __syncthreads();            // oct stores issued; LDS reads done
    ushort* xr = xt;            // reuse as [vox64][64ch]
    int cob = g*16 + q*4;       // MW==1
    #pragma unroll
    for (int nt=0; nt<4; nt++){
      int vox = nt*16 + n;
      uint2 pk;
      pk.x = packbf2((acc[0][nt].x + bias[cob+0])*0.25f, (acc[0][nt].y + bias[cob+1])*0.25f);
      pk.y = packbf2((acc[0][nt].z + bias[cob+2])*0.25f, (acc[0][nt].w + bias[cob+3])*0.25f);
      *reinterpret_cast<uint2*>(&xr[vox*64 + cob]) = pk;
    }
    __syncthreads();
    char* ob = (char*)((ushort*)outp + (size_t)call*CC*VV) + (size_t)v0*128;
    const char* lb = reinterpret_cast<const char*>(xr);
    #pragma unroll
    for (int k=0; k<2; k++){
      int idx = tid + k*256;    // 512 x uint4 = 8KB
      *reinterpret_cast<uint4*>(ob + idx*16) = *reinterpret_cast<const uint4*>(lb + idx*16);
    }
  }
}

// ---- 3x3x3 conv via implicit-GEMM MFMA, 4-z blocks, OCT staging ---------
// Block = 256 voxels (4z x 8y x 8x), halo 6x10x10 = 600 pos per ci-half.
// Staging: 4 groups x 600 pos of uint4 (16B = 8ch) per half -> 2400 items.
// Waves 2(m) x 2(z-pair), 8 n-tiles/wave. PREF 1: register prefetch of
// half1 during half0 compute. PREF 0: plain staged halves (lower VGPR).
template<int CO, int OUTPK, int PREF>
__global__ __launch_bounds__(256) void conv3_mfma(
    const uint* __restrict__ xpk,
    const uint* __restrict__ wA, const float* __restrict__ bias,
    void* __restrict__ outp)
{
  constexpr int MG = CO/16;
  constexpr int MROW = CO/32;
  __shared__ ushort xh[24576];   // 49152 B (staging uses 48000)
  int tid = threadIdx.x;
  int lane = tid & 63;
  int w = __builtin_amdgcn_readfirstlane(tid >> 6);
  int q = lane >> 4, n = lane & 15;
  int bid = blockIdx.x;           // 0..511
  int xcd = bid & 7, islot = bid >> 3;     // islot 0..63 = (by,bx)
  int call = xcd >> 2;
  int z0 = (xcd & 3) * 4;
  int by = (islot >> 3) << 3, bx = (islot & 7) << 3;

  const uint4* xinp = reinterpret_cast<const uint4*>(xpk) + (size_t)call*8*VV;

  int mbase = (w & 1) * MROW;
  int nzh = (w >> 1) * 2;         // first local z-slice owned by this wave
  int lo[8];
  #pragma unroll
  for (int nt=0;nt<8;nt++){
    int zi = nzh + (nt>>2);
    int vl = (nt&3)*16 + n;       // 0..63 within slice
    lo[nt] = (zi*100 + (vl>>3)*10 + (vl&7))*80 + q*16;
  }
  f32x4 acc[MROW][8];
  #pragma unroll
  for (int mr=0;mr<MROW;mr++)
    #pragma unroll
    for (int nt=0;nt<8;nt++){ acc[mr][nt].x=0.f; acc[mr][nt].y=0.f; acc[mr][nt].z=0.f; acc[mr][nt].w=0.f; }

  const char* ldsb = reinterpret_cast<const char*>(xh);
  const char* wac  = reinterpret_cast<const char*>(wA);

  auto compute_half = [&](int h){
    #pragma unroll 2
    for (int tap=0; tap<27; tap++){
      int dz = tap/9; int r9 = tap - dz*9; int dy = r9/3; int dxx = r9 - dy*3;
      int stepOff = (dz*100 + dy*10 + dxx)*80;
      int s = tap*2 + h;
      bf16x8 af[MROW];
      #pragma unroll
      for (int mr=0;mr<MROW;mr++)
        af[mr] = *reinterpret_cast<const bf16x8*>(wac + (size_t)((s*MG + mbase+mr)*64 + lane)*16);
      bf16x8 bf[8];
      #pragma unroll
      for (int nt=0;nt<8;nt++)
        bf[nt] = *reinterpret_cast<const bf16x8*>(ldsb + (lo[nt] + stepOff));
      #pragma unroll
      for (int mr=0;mr<MROW;mr++)
        #pragma unroll
        for (int nt=0;nt<8;nt++)
          acc[mr][nt] = __builtin_amdgcn_mfma_f32_16x16x32_bf16(af[mr], bf[nt], acc[mr][nt], 0, 0, 0);
    }
  };

  if constexpr (PREF){
    uint4 pq[10];
    auto load_half = [&](int h){
      #pragma unroll
      for (int k=0;k<10;k++){
        int it = tid + k*256;
        if (it < 2400){
          int cg = it/600; int pos = it - cg*600;
          int dz = pos/100; int rr = pos - dz*100; int dy = rr/10; int dxx = rr - dy*10;
          int gz = z0 + dz - 1, gy = by + dy - 1, gx = bx + dxx - 1;
          uint4 v; v.x = 0u; v.y = 0u; v.z = 0u; v.w = 0u;
          if (gz>=0 && gz<DD && gy>=0 && gy<HH && gx>=0 && gx<WW)
            v = xinp[(size_t)(h*4+cg)*VV + (size_t)((gz*HH+gy)*WW + gx)];
          pq[k] = v;
        }
      }
    };
    auto write_half = [&](){
      #pragma unroll
      for (int k=0;k<10;k++){
        int it = tid + k*256;
        if (it < 2400){
          int cg = it/600; int pos = it - cg*600;
          *reinterpret_cast<uint4*>(&xh[pos*40 + cg*8]) = pq[k];
        }
      }
    };
    load_half(0);
    write_half();
    __syncthreads();
    load_half(1);          // in flight during half-0 compute
    compute_half(0);
    __syncthreads();       // all waves done reading half 0
    write_half();
    __syncthreads();
    compute_half(1);
  } else {
    #pragma unroll 1
    for (int h=0; h<2; h++){
      if (h) __syncthreads();         // readers of half (h-1) done
      for (int k=0;k<10;k++){
        int it = tid + k*256;
        if (it < 2400){
          int cg = it/600; int pos = it - cg*600;
          int dz = pos/100; int rr = pos - dz*100; int dy = rr/10; int dxx = rr - dy*10;
          int gz = z0 + dz - 1, gy = by + dy - 1, gx = bx + dxx - 1;
          uint4 v; v.x = 0u; v.y = 0u; v.z = 0u; v.w = 0u;
          if (gz>=0 && gz<DD && gy>=0 && gy<HH && gx>=0 && gx<WW)
            v = xinp[(size_t)(h*4+cg)*VV + (size_t)((gz*HH+gy)*WW + gx)];
          *reinterpret_cast<uint4*>(&xh[pos*40 + cg*8]) = v;
        }
      }
      __syncthreads();
      compute_half(h);
    }
  }

  // epilogue: C/D col = n (voxel), row = q*4+rr (co)
  if (OUTPK == 1){
    #pragma unroll
    for (int mr=0; mr<MROW; mr++){
      int cob = (mbase+mr)*16 + q*4;
      #pragma unroll
      for (int nt=0; nt<8; nt++){
        int zi = nzh + (nt>>2);
        int vl = (nt&3)*16 + n;
        int vy = by + (vl>>3), vx = bx + (vl&7);
        size_t gv = (size_t)(((z0+zi)*HH + vy)*WW + vx);
        float r0 = acc[mr][nt].x + bias[cob+0];
        float r1 = acc[mr][nt].y + bias[cob+1];
        float r2 = acc[mr][nt].z + bias[cob+2];
        float r3 = acc[mr][nt].w + bias[cob+3];
        r0 = 0.5f*r0*(1.f + erff(r0*0.70710678118654752f));
        r1 = 0.5f*r1*(1.f + erff(r1*0.70710678118654752f));
        r2 = 0.5f*r2*(1.f + erff(r2*0.70710678118654752f));
        r3 = 0.5f*r3*(1.f + erff(r3*0.70710678118654752f));
        uint2 pk; pk.x = packbf2(r0,r1); pk.y = packbf2(r2,r3);
        uint* dst = (uint*)outp;
        *reinterpret_cast<uint2*>(dst + ((size_t)(call*8 + (cob>>3))*VV + gv)*4 + ((cob&4)>>1)) = pk;
      }
    }
  } else {
    // tanh -> LDS [vox256][96ch] (49,152 B) -> coalesced 1536B chunk stores
    __syncthreads();
    ushort* xr = xh;
    #pragma unroll
    for (int mr=0; mr<MROW; mr++){
      int cob = (mbase+mr)*16 + q*4;
      #pragma unroll
      for (int nt=0; nt<8; nt++){
        int row = (nzh + (nt>>2))*64 + (nt&3)*16 + n;   // zi*64 + y8*8 + x8
        uint2 pk;
        pk.x = packbf2(fast_tanh(acc[mr][nt].x), fast_tanh(acc[mr][nt].y));
        pk.y = packbf2(fast_tanh(acc[mr][nt].z), fast_tanh(acc[mr][nt].w));
        *reinterpret_cast<uint2*>(&xr[row*96 + cob]) = pk;
      }
    }
    __syncthreads();
    ushort* dst = (ushort*)outp + (size_t)call*96*VV;
    const char* lb = reinterpret_cast<const char*>(xr);
    #pragma unroll
    for (int k=0; k<12; k++){
      int idx = tid + k*256;             // 3072 x uint4 = 48KB
      int chunk = idx/96;                // 32 chunks: (zi,y8)
      int off = idx - chunk*96;
      int zi = chunk>>3, y8 = chunk&7;
      size_t gb = (size_t)(((z0+zi)*HH + by + y8)*WW + bx)*192 + (size_t)off*16;
      *reinterpret_cast<uint4*>((char*)dst + gb) = *reinterpret_cast<const uint4*>(lb + idx*16);
    }
  }
}

// ---- fused front-end -----------------------------------------------------
// [0,1024): conv1<128,0> (kv -> vols, mid -> out copy)
// [1024,3072): conv1<64,1> (q -> qbuf; also emits oct o0pk from its LDS tile)
// [3072,3288): wA1   [3288,3612): wA2   [3612,3620): wo   (tiny tail blocks)
__global__ __launch_bounds__(256) void fused_front(
    const float* __restrict__ occ, const float* __restrict__ prev,
    const float* __restrict__ mid, uint* __restrict__ o0pk,
    const float* __restrict__ off1w, uint* __restrict__ wA1,
    const float* __restrict__ off2w, uint* __restrict__ wA2,
    const float* __restrict__ outw,  uint* __restrict__ wo,
    const float* __restrict__ kvw,  const float* __restrict__ kvb,
    const float* __restrict__ qw,   const float* __restrict__ qb,
    void* __restrict__ vols, void* __restrict__ qbuf, float* __restrict__ out)
{
  __shared__ ushort lds[64*72];
  int b = blockIdx.x, tid = threadIdx.x;
  if (b < 1024){
    conv1_body<128,0>(b, tid, lds, mid, nullptr, kvw, kvb, vols, out, nullptr);
  } else if (b < 3072){
    conv1_body<64,1>(b-1024, tid, lds, occ, prev, qw, qb, qbuf, nullptr, o0pk);
  }
  else if (b < 3288){ repack_wmfma_body(off1w, wA1, 4, (b-3072)*256 + tid); }
  else if (b < 3612){ repack_wmfma_body(off2w, wA2, 6, (b-3288)*256 + tid); }
  else              { repack_w1_body(outw, wo, 4, (b-3612)*256 + tid); }
}

// ---- sampling geometry (replicates the reference's channel->axis swap) ---
struct Geom { int x0,x1,y0,y1,z0,z1; float wx,wy,wz; };
__device__ __forceinline__ Geom make_geom(float zb, float yb, float xb,
                                          float o0, float o1, float o2){
  float g0 = clampf(zb + o0*(1.f/16.f), -1.f, 1.f);
  float g1 = clampf(yb + o1*(1.f/64.f), -1.f, 1.f);
  float g2 = clampf(xb + o2*(1.f/64.f), -1.f, 1.f);
  float ix = (g0+1.f)*0.5f*63.f;    // in [0,63]
  float iy = (g1+1.f)*0.5f*63.f;
  float iz = (g2+1.f)*0.5f*15.f;    // in [0,15]
  float fx=floorf(ix), fy=floorf(iy), fz=floorf(iz);
  Geom g;
  g.wx = ix-fx; g.wy = iy-fy; g.wz = iz-fz;
  g.x0 = (int)fx; g.x1 = imin(g.x0+1, WW-1);   // float clamp bounds x0 in [0,63]
  g.y0 = (int)fy; g.y1 = imin(g.y0+1, HH-1);
  g.z0 = (int)fz; g.z1 = imin(g.z0+1, DD-1);
  return g;
}

// ---- sample + attention + MFMA out conv + BN + relu ----------------------
// 4-lane cooperative slots; compact vols [head][y][x][z][32ch] (64B lines,
// L2-resident). Per (ky,kx) corner-pair: 2x b128 loads (z0,z1 lines),
// 8x v_perm_b32 to form (ch@z0,ch@z1) pairs, 8x v_dot2_f32_bf16 against
// packed (wyx*wz0, wyx*wz1). Roles 0/1 = K, 2/3 = V. Out-conv uses the
// pre-packed wo fragments (contiguous 16B load — inline repack regressed).
__global__ __launch_bounds__(256) void sample_attn_kernel(
    const ushort* __restrict__ qbuf, const ushort* __restrict__ offbuf,
    const uint* __restrict__ vols, const uint* __restrict__ woA,
    const float* __restrict__ outb, const float* __restrict__ bng,
    const float* __restrict__ bnb, const float* __restrict__ bnm,
    const float* __restrict__ bnv, float* __restrict__ dout)
{
  __shared__ ushort fsb[16*72];   // fused attn output, bf16 [vox16][64ci], 144B rows
  int t = threadIdx.x;
  int lane = t & 63;
  int m = __builtin_amdgcn_readfirstlane(t >> 6);   // head
  int slot = lane >> 2;
  int r = lane & 3;
  int bid = blockIdx.x;
  int xcd = bid & 7, islot = bid >> 3;
  int call = islot >> 9;
  int z = xcd*2 + ((islot >> 8) & 1);
  int rem = islot & 255;
  int y = rem >> 2;
  int x0 = (rem & 3) << 4;
  int x = x0 + slot;
  int vbase = (z*HH + y)*WW + x0;
  int v = vbase + slot;

  const ushort* qb = qbuf   + (size_t)call*CC*VV;
  const ushort* ob = offbuf + (size_t)call*96*VV;

  // q half: roles 0/2 -> ch m*16+0..7, roles 1/3 -> +8..15 (one 16B load)
  uint4 qu = *reinterpret_cast<const uint4*>(qb + (size_t)v*64 + m*16 + (r&1)*8);
  float qf[8];
  qf[0]=bflo(qu.x); qf[1]=bfhi(qu.x); qf[2]=bflo(qu.y); qf[3]=bfhi(qu.y);
  qf[4]=bflo(qu.z); qf[5]=bfhi(qu.z); qf[6]=bflo(qu.w); qf[7]=bfhi(qu.w);

  // all 24 offsets for head m at voxel v: 3 x 16B loads
  uint ou[12];
  {
    const uint4* op4 = reinterpret_cast<const uint4*>(ob + (size_t)v*96 + m*24);
    uint4 a = op4[0], b4 = op4[1], c4 = op4[2];
    ou[0]=a.x;  ou[1]=a.y;  ou[2]=a.z;  ou[3]=a.w;
    ou[4]=b4.x; ou[5]=b4.y; ou[6]=b4.z; ou[7]=b4.w;
    ou[8]=c4.x; ou[9]=c4.y; ou[10]=c4.z; ou[11]=c4.w;
  }

  float zbf = -1.f + (float)z*(2.f/15.f);
  float ybf = -1.f + (float)y*(2.f/63.f);
  float xbf = -1.f + (float)x*(2.f/63.f);

  const char* volb = reinterpret_cast<const char*>(vols) + (size_t)m*VV*64;
  float roleK = (r < 2) ? 1.f : 0.f;
  float lrun = 0.f;
  float fused[8];
  #pragma unroll
  for (int c=0;c<8;c++) fused[c]=0.f;

  #pragma unroll
  for (int s=0;s<NSAMP;s++){
    int i0 = 3*s, i1 = 3*s+1, i2 = 3*s+2;          // static after unroll
    float o0 = (i0&1) ? bfhi(ou[i0>>1]) : bflo(ou[i0>>1]);
    float o1 = (i1&1) ? bfhi(ou[i1>>1]) : bflo(ou[i1>>1]);
    float o2 = (i2&1) ? bfhi(ou[i2>>1]) : bflo(ou[i2>>1]);
    Geom g = make_geom(zbf,ybf,xbf,o0,o1,o2);
    int tz0 = g.z0*64 + r*16;
    int tz1 = g.z1*64 + r*16;
    float wx1 = g.wx, wx0 = 1.f-g.wx;
    float wy1 = g.wy, wy0 = 1.f-g.wy;
    float wz1 = g.wz, wz0 = 1.f-g.wz;
    float acc[8];
    #pragma unroll
    for (int c=0;c<8;c++) acc[c]=0.f;
    #pragma unroll
    for (int ky=0;ky<2;ky++)
    #pragma unroll
    for (int kx=0;kx<2;kx++){
      int cy = ky? g.y1:g.y0, cx = kx? g.x1:g.x0;
      float wyx = (ky? wy1:wy0)*(kx? wx1:wx0);
      float a0 = wyx*wz0, a1 = wyx*wz1;
      uint wzp;
      asm("v_cvt_pk_bf16_f32 %0, %1, %2" : "=v"(wzp) : "v"(a0), "v"(a1));
      int tb = ((cy<<6) + cx) << 10;
      const char* p = volb + tb;
      uint4 u0 = *reinterpret_cast<const uint4*>(p + tz0);
      uint4 u1 = *reinterpret_cast<const uint4*>(p + tz1);
      uint plo, phi;
      plo = __builtin_amdgcn_perm(u1.x, u0.x, 0x05040100u);
      phi = __builtin_amdgcn_perm(u1.x, u0.x, 0x07060302u);
      asm("v_dot2_f32_bf16 %0, %1, %2, %0" : "+v"(acc[0]) : "v"(plo), "v"(wzp));
      asm("v_dot2_f32_bf16 %0, %1, %2, %0" : "+v"(acc[1]) : "v"(phi), "v"(wzp));
      plo = __builtin_amdgcn_perm(u1.y, u0.y, 0x05040100u);
      phi = __builtin_amdgcn_perm(u1.y, u0.y, 0x07060302u);
      asm("v_dot2_f32_bf16 %0, %1, %2, %0" : "+v"(acc[2]) : "v"(plo), "v"(wzp));
      asm("v_dot2_f32_bf16 %0, %1, %2, %0" : "+v"(acc[3]) : "v"(phi), "v"(wzp));
      plo = __builtin_amdgcn_perm(u1.z, u0.z, 0x05040100u);
      phi = __builtin_amdgcn_perm(u1.z, u0.z, 0x07060302u);
      asm("v_dot2_f32_bf16 %0, %1, %2, %0" : "+v"(acc[4]) : "v"(plo), "v"(wzp));
      asm("v_dot2_f32_bf16 %0, %1, %2, %0" : "+v"(acc[5]) : "v"(phi), "v"(wzp));
      plo = __builtin_amdgcn_perm(u1.w, u0.w, 0x05040100u);
      phi = __builtin_amdgcn_perm(u1.w, u0.w, 0x07060302u);
      asm("v_dot2_f32_bf16 %0, %1, %2, %0" : "+v"(acc[6]) : "v"(plo), "v"(wzp));
      asm("v_dot2_f32_bf16 %0, %1, %2, %0" : "+v"(acc[7]) : "v"(phi), "v"(wzp));
    }
    float h = qf[0]*acc[0]+qf[1]*acc[1]+qf[2]*acc[2]+qf[3]*acc[3]
            + qf[4]*acc[4]+qf[5]*acc[5]+qf[6]*acc[6]+qf[7]*acc[7];
    h *= roleK;                 // roles 2/3 contribute 0
    h += __shfl_xor(h, 1);      // sum K halves within role pair
    h += __shfl_xor(h, 2);      // broadcast to V lanes
    float e = __expf(h);
    lrun += e;
    #pragma unroll
    for (int c=0;c<8;c++) fused[c] += e*acc[c];
  }
  float isum = 1.f/lrun;
  if (r >= 2){
    uint4 pk;
    pk.x = packbf2(fused[0]*isum, fused[1]*isum);
    pk.y = packbf2(fused[2]*isum, fused[3]*isum);
    pk.z = packbf2(fused[4]*isum, fused[5]*isum);
    pk.w = packbf2(fused[6]*isum, fused[7]*isum);
    *reinterpret_cast<uint4*>(&fsb[slot*72 + m*16 + (r&1)*8]) = pk;
  }
  __syncthreads();

  // out 1x1 conv via MFMA: wave m computes co-tile m (16 co) x 16 vox
  int qq = lane >> 4, n = lane & 15;
  f32x4 acco;
  acco.x=0.f; acco.y=0.f; acco.z=0.f; acco.w=0.f;
  const char* ldsb = reinterpret_cast<const char*>(fsb);
  const char* wac  = reinterpret_cast<const char*>(woA);
  #pragma unroll
  for (int ks=0; ks<2; ks++){
    bf16x8 af = *reinterpret_cast<const bf16x8*>(wac + (size_t)((ks*4 + m)*64 + lane)*16);
    bf16x8 bfv = *reinterpret_cast<const bf16x8*>(ldsb + (n*144 + qq*16 + ks*64));
    acco = __builtin_amdgcn_mfma_f32_16x16x32_bf16(af, bfv, acco, 0, 0, 0);
  }
  int choff = 64 + call*64;
  #pragma unroll
  for (int rr=0; rr<4; rr++){
    int co = m*16 + qq*4 + rr;
    float inv = rsqrtf(bnv[co] + 1e-5f) * bng[co];
    float val = (acco[rr] + outb[co] - bnm[co]) * inv + bnb[co];
    val = fmaxf(val, 0.f);
    dout[(size_t)(choff+co)*VV + vbase + n] = val;
  }
}

extern "C" void kernel_launch(void* const* d_in, const int* in_sizes, int n_in,
                              void* d_out, int out_size, void* d_ws, size_t ws_size,
                              hipStream_t stream){
  (void)in_sizes; (void)n_in; (void)out_size; (void)ws_size;
  const float* mid  = (const float*)d_in[0];
  const float* occ  = (const float*)d_in[1];
  const float* prev = (const float*)d_in[2];
  const float* off1w= (const float*)d_in[3];
  const float* off1b= (const float*)d_in[4];
  const float* off2w= (const float*)d_in[5];
  const float* kvw  = (const float*)d_in[6];
  const float* kvb  = (const float*)d_in[7];
  const float* qw   = (const float*)d_in[8];
  const float* qb   = (const float*)d_in[9];
  const float* outw = (const float*)d_in[10];
  const float* outb = (const float*)d_in[11];
  const float* bng  = (const float*)d_in[12];
  const float* bnb  = (const float*)d_in[13];
  const float* bnm  = (const float*)d_in[14];
  const float* bnv  = (const float*)d_in[15];
  float* out = (float*)d_out;

  uint*   vols  = (uint*)d_ws;                          // 4*VV*16 uints   (16.8 MB)
  ushort* qbuf  = (ushort*)(vols + (size_t)4*VV*16);    // 2*64*VV ushort  (16.8 MB)
  uint*   o1pk  = (uint*)(qbuf + (size_t)2*CC*VV);      // 2*32*VV uint    (16.8 MB)
  ushort* offb  = (ushort*)(o1pk + (size_t)2*32*VV);    // 2*96*VV ushort  (25.2 MB)
  uint*   wA1   = (uint*)(offb + (size_t)2*96*VV);      // 55296
  uint*   wA2   = wA1 + 55296;                          // 82944
  uint*   wo    = wA2 + 82944;                          // 2048
  uint*   o0pk  = wo  + 2048;                           // 2*32*VV uint    (16.8 MB)

  fused_front<<<3620, 256, 0, stream>>>(occ, prev, mid, o0pk,
      off1w, wA1, off2w, wA2, outw, wo, kvw, kvb, qw, qb,
      (void*)vols, (void*)qbuf, out);
  conv3_mfma<64,1,1><<<512, 256, 0, stream>>>(o0pk, wA1, off1b, (void*)o1pk);
  conv3_mfma<96,0,0><<<512, 256, 0, stream>>>(o1pk, wA2, off1b, (void*)offb);
  sample_attn_kernel<<<8192, 256, 0, stream>>>(qbuf, offb, vols, wo,
      outb, bng, bnb, bnm, bnv, out);
}

// Round 11
// 303.484 us; speedup vs baseline: 1.4278x; 1.4278x over previous
//
#include <hip/hip_runtime.h>
#include <math.h>

#define DD 16
#define HH 64
#define WW 64
#define VV (DD*HH*WW)      // 65536
#define CC 64
#define NHEADS 4
#define NSAMP 8
#define HDIM 16

typedef unsigned int uint;
typedef unsigned short ushort;
typedef __attribute__((ext_vector_type(8))) short bf16x8;
typedef __attribute__((ext_vector_type(4))) float f32x4;

__device__ __forceinline__ float clampf(float v, float lo, float hi){ return fminf(fmaxf(v, lo), hi); }
__device__ __forceinline__ int imin(int a, int b){ return a < b ? a : b; }

// bf16 helpers (RNE)
__device__ __forceinline__ ushort f2bf(float f){
  uint u = __float_as_uint(f);
  uint r = (u + 0x7fffu + ((u>>16)&1u)) >> 16;
  return (ushort)r;
}
__device__ __forceinline__ uint packbf2(float a, float b){
  return (uint)f2bf(a) | ((uint)f2bf(b) << 16);
}
__device__ __forceinline__ float bflo(uint u){ return __uint_as_float(u << 16); }
__device__ __forceinline__ float bfhi(uint u){ return __uint_as_float(u & 0xffff0000u); }
__device__ __forceinline__ float bf2f(ushort u){ return __uint_as_float((uint)u << 16); }

__device__ __forceinline__ float fast_tanh(float x){
  float e = __expf(2.f*x);
  return 1.f - 2.f/(e + 1.f);
}

// ---- inline 1x1 A-fragment from raw fp32 [co][64ci] weights --------------
__device__ __forceinline__ bf16x8 make_af(const float* __restrict__ w, int mt, int ks, int lane){
  const float* p = w + (size_t)(mt*16 + (lane&15))*CC + ks*32 + ((lane>>4)<<3);
  float4 f0 = *reinterpret_cast<const float4*>(p);
  float4 f1 = *reinterpret_cast<const float4*>(p+4);
  union { uint4 u; bf16x8 b; } r;
  r.u.x = packbf2(f0.x, f0.y); r.u.y = packbf2(f0.z, f0.w);
  r.u.z = packbf2(f1.x, f1.y); r.u.w = packbf2(f1.z, f1.w);
  return r.b;
}

// ---- weight repack bodies ------------------------------------------------
__device__ __forceinline__ void repack_wmfma_body(const float* __restrict__ w,
                                                  uint* __restrict__ o, int MG, int U){
  int j2 = U & 3;
  int m  = (U>>2) & 15;
  int q  = (U>>6) & 3;
  int rest = U >> 8;          // s*MG + g
  int g = rest % MG;
  int s = rest / MG;
  int tap = s >> 1, h = s & 1;
  int co = g*16 + m;
  int ci = h*32 + q*8 + j2*2;
  int base = co*1728 + ci*27 + tap;
  o[U] = packbf2(w[base], w[base + 27]);
}
__device__ __forceinline__ void repack_w1_body(const float* __restrict__ w,
                                               uint* __restrict__ o, int MT, int U){
  int j2 = U & 3;
  int lane = (U>>2) & 63;
  int frag = U >> 8;
  int mt = frag % MT;
  int ks = frag / MT;
  int q = lane >> 4, m = lane & 15;
  int co = mt*16 + m;
  int ci = ks*32 + q*8 + j2*2;
  o[U] = packbf2(w[co*CC + ci], w[co*CC + ci + 1]);
}

// ---- 1x1 conv body (MFMA), raw weights, LDS passed in --------------------
// EPI 0: fp32 input (mid); +bias -> vols[head][y][x][z][32ch]; copies mid->mcopy.
// EPI 1: fp32 input (occ/prev by call); also emits the oct-packed input tile
//        to o0out (folds the pack pass); (acc+bias)*0.25 -> q [call][vox][64ch]
template<int CO, int EPI>
__device__ void conv1_body(
    int bid, int tid, ushort* __restrict__ xt,
    const float* __restrict__ xa, const float* __restrict__ xb,
    const float* __restrict__ wraw, const float* __restrict__ bias,
    void* __restrict__ outp, float* __restrict__ mcopy,
    uint* __restrict__ o0out)
{
  constexpr int MT = CO/16;
  constexpr int MW = MT/4;
  int lane = tid & 63;
  int g = __builtin_amdgcn_readfirstlane(tid >> 6);
  int q = lane >> 4, n = lane & 15;
  int call = bid >> 10;
  int v0 = (bid & 1023) * 64;
  bf16x8 afr[2][MW];
  #pragma unroll
  for (int ks=0; ks<2; ks++)
    #pragma unroll
    for (int mw=0; mw<MW; mw++)
      afr[ks][mw] = make_af(wraw, g*MW+mw, ks, lane);
  const float* x = call ? xb : xa;
  for (int it = tid; it < 64*32; it += 256){
    int vox = it & 63; int cp = it >> 6;
    float a = x[(size_t)(2*cp)*VV + v0 + vox];
    float b = x[(size_t)(2*cp+1)*VV + v0 + vox];
    if constexpr (EPI == 0){
      mcopy[(size_t)(2*cp)*VV + v0 + vox] = a;
      mcopy[(size_t)(2*cp+1)*VV + v0 + vox] = b;
    }
    *reinterpret_cast<uint*>(&xt[vox*72 + 2*cp]) = packbf2(a,b);
  }
  __syncthreads();
  if constexpr (EPI == 1){
    // LDS row = 32 consecutive dwords = exactly the oct layout for this voxel.
    uint4* ob = reinterpret_cast<uint4*>(o0out) + (size_t)call*8*VV + v0;
    #pragma unroll
    for (int k=0; k<2; k++){
      int it = tid + k*256;    // 512 items: vox 64 x cg 8
      int vox = it & 63; int cg = it >> 6;
      ob[(size_t)cg*VV + vox] = *reinterpret_cast<const uint4*>(
          reinterpret_cast<const char*>(xt) + vox*144 + cg*16);
    }
  }
  f32x4 acc[MW][4];
  #pragma unroll
  for (int mw=0;mw<MW;mw++)
    #pragma unroll
    for (int nt=0;nt<4;nt++){ acc[mw][nt].x=0.f; acc[mw][nt].y=0.f; acc[mw][nt].z=0.f; acc[mw][nt].w=0.f; }
  const char* ldsb = reinterpret_cast<const char*>(xt);
  #pragma unroll
  for (int ks=0; ks<2; ks++){
    bf16x8 bfr[4];
    #pragma unroll
    for (int nt=0; nt<4; nt++)
      bfr[nt] = *reinterpret_cast<const bf16x8*>(ldsb + ((nt*16+n)*144 + q*16 + ks*64));
    #pragma unroll
    for (int mw=0; mw<MW; mw++)
      #pragma unroll
      for (int nt=0; nt<4; nt++)
        acc[mw][nt] = __builtin_amdgcn_mfma_f32_16x16x32_bf16(afr[ks][mw], bfr[nt], acc[mw][nt], 0, 0, 0);
  }
  if constexpr (EPI == 0){
    #pragma unroll
    for (int mw=0; mw<MW; mw++){
      int mt = g*MW + mw;
      int cob = mt*16 + q*4;
      #pragma unroll
      for (int nt=0; nt<4; nt++){
        int v = v0 + nt*16 + n;
        float r0 = acc[mw][nt].x + bias[cob+0];
        float r1 = acc[mw][nt].y + bias[cob+1];
        float r2 = acc[mw][nt].z + bias[cob+2];
        float r3 = acc[mw][nt].w + bias[cob+3];
        int z = v >> 12, y = (v >> 6) & 63, xx = v & 63;
        int head = cob >> 5;
        uint* vols = (uint*)outp;
        uint2 pk; pk.x = packbf2(r0,r1); pk.y = packbf2(r2,r3);
        *reinterpret_cast<uint2*>(vols + ((size_t)head*VV + (size_t)(y*WW+xx)*DD + z)*16 + ((cob&31)>>1)) = pk;
      }
    }
  } else {
    __syncthreads();            // oct stores issued; LDS reads done
    ushort* xr = xt;            // reuse as [vox64][64ch]
    int cob = g*16 + q*4;       // MW==1
    #pragma unroll
    for (int nt=0; nt<4; nt++){
      int vox = nt*16 + n;
      uint2 pk;
      pk.x = packbf2((acc[0][nt].x + bias[cob+0])*0.25f, (acc[0][nt].y + bias[cob+1])*0.25f);
      pk.y = packbf2((acc[0][nt].z + bias[cob+2])*0.25f, (acc[0][nt].w + bias[cob+3])*0.25f);
      *reinterpret_cast<uint2*>(&xr[vox*64 + cob]) = pk;
    }
    __syncthreads();
    char* ob = (char*)((ushort*)outp + (size_t)call*CC*VV) + (size_t)v0*128;
    const char* lb = reinterpret_cast<const char*>(xr);
    #pragma unroll
    for (int k=0; k<2; k++){
      int idx = tid + k*256;    // 512 x uint4 = 8KB
      *reinterpret_cast<uint4*>(ob + idx*16) = *reinterpret_cast<const uint4*>(lb + idx*16);
    }
  }
}

// ---- 3x3x3 conv via implicit-GEMM MFMA, 4-z blocks, OCT staging ---------
// Block = 256 voxels (4z x 8y x 8x), halo 6x10x10 = 600 pos per ci-half.
// Staging: 4 groups x 600 pos of uint4 (16B = 8ch) per half -> 2400 items.
// Waves 2(m) x 2(z-pair), 8 n-tiles/wave. PREF 1: register prefetch of
// half1 during half0 compute. PREF 0: plain staged halves (lower VGPR).
template<int CO, int OUTPK, int PREF>
__global__ __launch_bounds__(256) void conv3_mfma(
    const uint* __restrict__ xpk,
    const uint* __restrict__ wA, const float* __restrict__ bias,
    void* __restrict__ outp)
{
  constexpr int MG = CO/16;
  constexpr int MROW = CO/32;
  __shared__ ushort xh[24576];   // 49152 B (staging uses 48000)
  int tid = threadIdx.x;
  int lane = tid & 63;
  int w = __builtin_amdgcn_readfirstlane(tid >> 6);
  int q = lane >> 4, n = lane & 15;
  int bid = blockIdx.x;           // 0..511
  int xcd = bid & 7, islot = bid >> 3;     // islot 0..63 = (by,bx)
  int call = xcd >> 2;
  int z0 = (xcd & 3) * 4;
  int by = (islot >> 3) << 3, bx = (islot & 7) << 3;

  const uint4* xinp = reinterpret_cast<const uint4*>(xpk) + (size_t)call*8*VV;

  int mbase = (w & 1) * MROW;
  int nzh = (w >> 1) * 2;         // first local z-slice owned by this wave
  int lo[8];
  #pragma unroll
  for (int nt=0;nt<8;nt++){
    int zi = nzh + (nt>>2);
    int vl = (nt&3)*16 + n;       // 0..63 within slice
    lo[nt] = (zi*100 + (vl>>3)*10 + (vl&7))*80 + q*16;
  }
  f32x4 acc[MROW][8];
  #pragma unroll
  for (int mr=0;mr<MROW;mr++)
    #pragma unroll
    for (int nt=0;nt<8;nt++){ acc[mr][nt].x=0.f; acc[mr][nt].y=0.f; acc[mr][nt].z=0.f; acc[mr][nt].w=0.f; }

  const char* ldsb = reinterpret_cast<const char*>(xh);
  const char* wac  = reinterpret_cast<const char*>(wA);

  auto compute_half = [&](int h){
    #pragma unroll 2
    for (int tap=0; tap<27; tap++){
      int dz = tap/9; int r9 = tap - dz*9; int dy = r9/3; int dxx = r9 - dy*3;
      int stepOff = (dz*100 + dy*10 + dxx)*80;
      int s = tap*2 + h;
      bf16x8 af[MROW];
      #pragma unroll
      for (int mr=0;mr<MROW;mr++)
        af[mr] = *reinterpret_cast<const bf16x8*>(wac + (size_t)((s*MG + mbase+mr)*64 + lane)*16);
      bf16x8 bf[8];
      #pragma unroll
      for (int nt=0;nt<8;nt++)
        bf[nt] = *reinterpret_cast<const bf16x8*>(ldsb + (lo[nt] + stepOff));
      #pragma unroll
      for (int mr=0;mr<MROW;mr++)
        #pragma unroll
        for (int nt=0;nt<8;nt++)
          acc[mr][nt] = __builtin_amdgcn_mfma_f32_16x16x32_bf16(af[mr], bf[nt], acc[mr][nt], 0, 0, 0);
    }
  };

  if constexpr (PREF){
    uint4 pq[10];
    auto load_half = [&](int h){
      #pragma unroll
      for (int k=0;k<10;k++){
        int it = tid + k*256;
        if (it < 2400){
          int cg = it/600; int pos = it - cg*600;
          int dz = pos/100; int rr = pos - dz*100; int dy = rr/10; int dxx = rr - dy*10;
          int gz = z0 + dz - 1, gy = by + dy - 1, gx = bx + dxx - 1;
          uint4 v; v.x = 0u; v.y = 0u; v.z = 0u; v.w = 0u;
          if (gz>=0 && gz<DD && gy>=0 && gy<HH && gx>=0 && gx<WW)
            v = xinp[(size_t)(h*4+cg)*VV + (size_t)((gz*HH+gy)*WW + gx)];
          pq[k] = v;
        }
      }
    };
    auto write_half = [&](){
      #pragma unroll
      for (int k=0;k<10;k++){
        int it = tid + k*256;
        if (it < 2400){
          int cg = it/600; int pos = it - cg*600;
          *reinterpret_cast<uint4*>(&xh[pos*40 + cg*8]) = pq[k];
        }
      }
    };
    load_half(0);
    write_half();
    __syncthreads();
    load_half(1);          // in flight during half-0 compute
    compute_half(0);
    __syncthreads();       // all waves done reading half 0
    write_half();
    __syncthreads();
    compute_half(1);
  } else {
    #pragma unroll 1
    for (int h=0; h<2; h++){
      if (h) __syncthreads();         // readers of half (h-1) done
      for (int k=0;k<10;k++){
        int it = tid + k*256;
        if (it < 2400){
          int cg = it/600; int pos = it - cg*600;
          int dz = pos/100; int rr = pos - dz*100; int dy = rr/10; int dxx = rr - dy*10;
          int gz = z0 + dz - 1, gy = by + dy - 1, gx = bx + dxx - 1;
          uint4 v; v.x = 0u; v.y = 0u; v.z = 0u; v.w = 0u;
          if (gz>=0 && gz<DD && gy>=0 && gy<HH && gx>=0 && gx<WW)
            v = xinp[(size_t)(h*4+cg)*VV + (size_t)((gz*HH+gy)*WW + gx)];
          *reinterpret_cast<uint4*>(&xh[pos*40 + cg*8]) = v;
        }
      }
      __syncthreads();
      compute_half(h);
    }
  }

  // epilogue: C/D col = n (voxel), row = q*4+rr (co)
  if (OUTPK == 1){
    #pragma unroll
    for (int mr=0; mr<MROW; mr++){
      int cob = (mbase+mr)*16 + q*4;
      #pragma unroll
      for (int nt=0; nt<8; nt++){
        int zi = nzh + (nt>>2);
        int vl = (nt&3)*16 + n;
        int vy = by + (vl>>3), vx = bx + (vl&7);
        size_t gv = (size_t)(((z0+zi)*HH + vy)*WW + vx);
        float r0 = acc[mr][nt].x + bias[cob+0];
        float r1 = acc[mr][nt].y + bias[cob+1];
        float r2 = acc[mr][nt].z + bias[cob+2];
        float r3 = acc[mr][nt].w + bias[cob+3];
        r0 = 0.5f*r0*(1.f + erff(r0*0.70710678118654752f));
        r1 = 0.5f*r1*(1.f + erff(r1*0.70710678118654752f));
        r2 = 0.5f*r2*(1.f + erff(r2*0.70710678118654752f));
        r3 = 0.5f*r3*(1.f + erff(r3*0.70710678118654752f));
        uint2 pk; pk.x = packbf2(r0,r1); pk.y = packbf2(r2,r3);
        uint* dst = (uint*)outp;
        *reinterpret_cast<uint2*>(dst + ((size_t)(call*8 + (cob>>3))*VV + gv)*4 + ((cob&4)>>1)) = pk;
      }
    }
  } else {
    // tanh -> LDS [vox256][96ch] (49,152 B) -> coalesced 1536B chunk stores
    __syncthreads();
    ushort* xr = xh;
    #pragma unroll
    for (int mr=0; mr<MROW; mr++){
      int cob = (mbase+mr)*16 + q*4;
      #pragma unroll
      for (int nt=0; nt<8; nt++){
        int row = (nzh + (nt>>2))*64 + (nt&3)*16 + n;   // zi*64 + y8*8 + x8
        uint2 pk;
        pk.x = packbf2(fast_tanh(acc[mr][nt].x), fast_tanh(acc[mr][nt].y));
        pk.y = packbf2(fast_tanh(acc[mr][nt].z), fast_tanh(acc[mr][nt].w));
        *reinterpret_cast<uint2*>(&xr[row*96 + cob]) = pk;
      }
    }
    __syncthreads();
    ushort* dst = (ushort*)outp + (size_t)call*96*VV;
    const char* lb = reinterpret_cast<const char*>(xr);
    #pragma unroll
    for (int k=0; k<12; k++){
      int idx = tid + k*256;             // 3072 x uint4 = 48KB
      int chunk = idx/96;                // 32 chunks: (zi,y8)
      int off = idx - chunk*96;
      int zi = chunk>>3, y8 = chunk&7;
      size_t gb = (size_t)(((z0+zi)*HH + by + y8)*WW + bx)*192 + (size_t)off*16;
      *reinterpret_cast<uint4*>((char*)dst + gb) = *reinterpret_cast<const uint4*>(lb + idx*16);
    }
  }
}

// ---- fused front-end -----------------------------------------------------
// [0,1024): conv1<128,0> (kv -> vols, mid -> out copy)
// [1024,3072): conv1<64,1> (q -> qbuf; also emits oct o0pk from its LDS tile)
// [3072,3288): wA1   [3288,3612): wA2   [3612,3620): wo   (tiny tail blocks)
__global__ __launch_bounds__(256) void fused_front(
    const float* __restrict__ occ, const float* __restrict__ prev,
    const float* __restrict__ mid, uint* __restrict__ o0pk,
    const float* __restrict__ off1w, uint* __restrict__ wA1,
    const float* __restrict__ off2w, uint* __restrict__ wA2,
    const float* __restrict__ outw,  uint* __restrict__ wo,
    const float* __restrict__ kvw,  const float* __restrict__ kvb,
    const float* __restrict__ qw,   const float* __restrict__ qb,
    void* __restrict__ vols, void* __restrict__ qbuf, float* __restrict__ out)
{
  __shared__ ushort lds[64*72];
  int b = blockIdx.x, tid = threadIdx.x;
  if (b < 1024){
    conv1_body<128,0>(b, tid, lds, mid, nullptr, kvw, kvb, vols, out, nullptr);
  } else if (b < 3072){
    conv1_body<64,1>(b-1024, tid, lds, occ, prev, qw, qb, qbuf, nullptr, o0pk);
  }
  else if (b < 3288){ repack_wmfma_body(off1w, wA1, 4, (b-3072)*256 + tid); }
  else if (b < 3612){ repack_wmfma_body(off2w, wA2, 6, (b-3288)*256 + tid); }
  else              { repack_w1_body(outw, wo, 4, (b-3612)*256 + tid); }
}

// ---- sampling geometry (replicates the reference's channel->axis swap) ---
struct Geom { int x0,x1,y0,y1,z0,z1; float wx,wy,wz; };
__device__ __forceinline__ Geom make_geom(float zb, float yb, float xb,
                                          float o0, float o1, float o2){
  float g0 = clampf(zb + o0*(1.f/16.f), -1.f, 1.f);
  float g1 = clampf(yb + o1*(1.f/64.f), -1.f, 1.f);
  float g2 = clampf(xb + o2*(1.f/64.f), -1.f, 1.f);
  float ix = (g0+1.f)*0.5f*63.f;    // in [0,63]
  float iy = (g1+1.f)*0.5f*63.f;
  float iz = (g2+1.f)*0.5f*15.f;    // in [0,15]
  float fx=floorf(ix), fy=floorf(iy), fz=floorf(iz);
  Geom g;
  g.wx = ix-fx; g.wy = iy-fy; g.wz = iz-fz;
  g.x0 = (int)fx; g.x1 = imin(g.x0+1, WW-1);   // float clamp bounds x0 in [0,63]
  g.y0 = (int)fy; g.y1 = imin(g.y0+1, HH-1);
  g.z0 = (int)fz; g.z1 = imin(g.z0+1, DD-1);
  return g;
}

// ---- sample + attention + MFMA out conv + BN + relu ----------------------
// 4-lane cooperative slots; compact vols [head][y][x][z][32ch] (64B lines,
// L2-resident). Per (ky,kx) corner-pair: 2x b128 loads (z0,z1 lines),
// 8x v_perm_b32 to form (ch@z0,ch@z1) pairs, 8x v_dot2_f32_bf16 against
// packed (wyx*wz0, wyx*wz1). Roles 0/1 = K, 2/3 = V. Out-conv uses the
// pre-packed wo fragments (contiguous 16B load — inline repack regressed).
__global__ __launch_bounds__(256) void sample_attn_kernel(
    const ushort* __restrict__ qbuf, const ushort* __restrict__ offbuf,
    const uint* __restrict__ vols, const uint* __restrict__ woA,
    const float* __restrict__ outb, const float* __restrict__ bng,
    const float* __restrict__ bnb, const float* __restrict__ bnm,
    const float* __restrict__ bnv, float* __restrict__ dout)
{
  __shared__ ushort fsb[16*72];   // fused attn output, bf16 [vox16][64ci], 144B rows
  int t = threadIdx.x;
  int lane = t & 63;
  int m = __builtin_amdgcn_readfirstlane(t >> 6);   // head
  int slot = lane >> 2;
  int r = lane & 3;
  int bid = blockIdx.x;
  int xcd = bid & 7, islot = bid >> 3;
  int call = islot >> 9;
  int z = xcd*2 + ((islot >> 8) & 1);
  int rem = islot & 255;
  int y = rem >> 2;
  int x0 = (rem & 3) << 4;
  int x = x0 + slot;
  int vbase = (z*HH + y)*WW + x0;
  int v = vbase + slot;

  const ushort* qb = qbuf   + (size_t)call*CC*VV;
  const ushort* ob = offbuf + (size_t)call*96*VV;

  // q half: roles 0/2 -> ch m*16+0..7, roles 1/3 -> +8..15 (one 16B load)
  uint4 qu = *reinterpret_cast<const uint4*>(qb + (size_t)v*64 + m*16 + (r&1)*8);
  float qf[8];
  qf[0]=bflo(qu.x); qf[1]=bfhi(qu.x); qf[2]=bflo(qu.y); qf[3]=bfhi(qu.y);
  qf[4]=bflo(qu.z); qf[5]=bfhi(qu.z); qf[6]=bflo(qu.w); qf[7]=bfhi(qu.w);

  // all 24 offsets for head m at voxel v: 3 x 16B loads
  uint ou[12];
  {
    const uint4* op4 = reinterpret_cast<const uint4*>(ob + (size_t)v*96 + m*24);
    uint4 a = op4[0], b4 = op4[1], c4 = op4[2];
    ou[0]=a.x;  ou[1]=a.y;  ou[2]=a.z;  ou[3]=a.w;
    ou[4]=b4.x; ou[5]=b4.y; ou[6]=b4.z; ou[7]=b4.w;
    ou[8]=c4.x; ou[9]=c4.y; ou[10]=c4.z; ou[11]=c4.w;
  }

  float zbf = -1.f + (float)z*(2.f/15.f);
  float ybf = -1.f + (float)y*(2.f/63.f);
  float xbf = -1.f + (float)x*(2.f/63.f);

  const char* volb = reinterpret_cast<const char*>(vols) + (size_t)m*VV*64;
  float roleK = (r < 2) ? 1.f : 0.f;
  float lrun = 0.f;
  float fused[8];
  #pragma unroll
  for (int c=0;c<8;c++) fused[c]=0.f;

  #pragma unroll
  for (int s=0;s<NSAMP;s++){
    int i0 = 3*s, i1 = 3*s+1, i2 = 3*s+2;          // static after unroll
    float o0 = (i0&1) ? bfhi(ou[i0>>1]) : bflo(ou[i0>>1]);
    float o1 = (i1&1) ? bfhi(ou[i1>>1]) : bflo(ou[i1>>1]);
    float o2 = (i2&1) ? bfhi(ou[i2>>1]) : bflo(ou[i2>>1]);
    Geom g = make_geom(zbf,ybf,xbf,o0,o1,o2);
    int tz0 = g.z0*64 + r*16;
    int tz1 = g.z1*64 + r*16;
    float wx1 = g.wx, wx0 = 1.f-g.wx;
    float wy1 = g.wy, wy0 = 1.f-g.wy;
    float wz1 = g.wz, wz0 = 1.f-g.wz;
    float acc[8];
    #pragma unroll
    for (int c=0;c<8;c++) acc[c]=0.f;
    #pragma unroll
    for (int ky=0;ky<2;ky++)
    #pragma unroll
    for (int kx=0;kx<2;kx++){
      int cy = ky? g.y1:g.y0, cx = kx? g.x1:g.x0;
      float wyx = (ky? wy1:wy0)*(kx? wx1:wx0);
      float a0 = wyx*wz0, a1 = wyx*wz1;
      uint wzp;
      asm("v_cvt_pk_bf16_f32 %0, %1, %2" : "=v"(wzp) : "v"(a0), "v"(a1));
      int tb = ((cy<<6) + cx) << 10;
      const char* p = volb + tb;
      uint4 u0 = *reinterpret_cast<const uint4*>(p + tz0);
      uint4 u1 = *reinterpret_cast<const uint4*>(p + tz1);
      uint plo, phi;
      plo = __builtin_amdgcn_perm(u1.x, u0.x, 0x05040100u);
      phi = __builtin_amdgcn_perm(u1.x, u0.x, 0x07060302u);
      asm("v_dot2_f32_bf16 %0, %1, %2, %0" : "+v"(acc[0]) : "v"(plo), "v"(wzp));
      asm("v_dot2_f32_bf16 %0, %1, %2, %0" : "+v"(acc[1]) : "v"(phi), "v"(wzp));
      plo = __builtin_amdgcn_perm(u1.y, u0.y, 0x05040100u);
      phi = __builtin_amdgcn_perm(u1.y, u0.y, 0x07060302u);
      asm("v_dot2_f32_bf16 %0, %1, %2, %0" : "+v"(acc[2]) : "v"(plo), "v"(wzp));
      asm("v_dot2_f32_bf16 %0, %1, %2, %0" : "+v"(acc[3]) : "v"(phi), "v"(wzp));
      plo = __builtin_amdgcn_perm(u1.z, u0.z, 0x05040100u);
      phi = __builtin_amdgcn_perm(u1.z, u0.z, 0x07060302u);
      asm("v_dot2_f32_bf16 %0, %1, %2, %0" : "+v"(acc[4]) : "v"(plo), "v"(wzp));
      asm("v_dot2_f32_bf16 %0, %1, %2, %0" : "+v"(acc[5]) : "v"(phi), "v"(wzp));
      plo = __builtin_amdgcn_perm(u1.w, u0.w, 0x05040100u);
      phi = __builtin_amdgcn_perm(u1.w, u0.w, 0x07060302u);
      asm("v_dot2_f32_bf16 %0, %1, %2, %0" : "+v"(acc[6]) : "v"(plo), "v"(wzp));
      asm("v_dot2_f32_bf16 %0, %1, %2, %0" : "+v"(acc[7]) : "v"(phi), "v"(wzp));
    }
    float h = qf[0]*acc[0]+qf[1]*acc[1]+qf[2]*acc[2]+qf[3]*acc[3]
            + qf[4]*acc[4]+qf[5]*acc[5]+qf[6]*acc[6]+qf[7]*acc[7];
    h *= roleK;                 // roles 2/3 contribute 0
    h += __shfl_xor(h, 1);      // sum K halves within role pair
    h += __shfl_xor(h, 2);      // broadcast to V lanes
    float e = __expf(h);
    lrun += e;
    #pragma unroll
    for (int c=0;c<8;c++) fused[c] += e*acc[c];
  }
  float isum = 1.f/lrun;
  if (r >= 2){
    uint4 pk;
    pk.x = packbf2(fused[0]*isum, fused[1]*isum);
    pk.y = packbf2(fused[2]*isum, fused[3]*isum);
    pk.z = packbf2(fused[4]*isum, fused[5]*isum);
    pk.w = packbf2(fused[6]*isum, fused[7]*isum);
    *reinterpret_cast<uint4*>(&fsb[slot*72 + m*16 + (r&1)*8]) = pk;
  }
  __syncthreads();

  // out 1x1 conv via MFMA: wave m computes co-tile m (16 co) x 16 vox
  int qq = lane >> 4, n = lane & 15;
  f32x4 acco;
  acco.x=0.f; acco.y=0.f; acco.z=0.f; acco.w=0.f;
  const char* ldsb = reinterpret_cast<const char*>(fsb);
  const char* wac  = reinterpret_cast<const char*>(woA);
  #pragma unroll
  for (int ks=0; ks<2; ks++){
    bf16x8 af = *reinterpret_cast<const bf16x8*>(wac + (size_t)((ks*4 + m)*64 + lane)*16);
    bf16x8 bfv = *reinterpret_cast<const bf16x8*>(ldsb + (n*144 + qq*16 + ks*64));
    acco = __builtin_amdgcn_mfma_f32_16x16x32_bf16(af, bfv, acco, 0, 0, 0);
  }
  int choff = 64 + call*64;
  #pragma unroll
  for (int rr=0; rr<4; rr++){
    int co = m*16 + qq*4 + rr;
    float inv = rsqrtf(bnv[co] + 1e-5f) * bng[co];
    float val = (acco[rr] + outb[co] - bnm[co]) * inv + bnb[co];
    val = fmaxf(val, 0.f);
    dout[(size_t)(choff+co)*VV + vbase + n] = val;
  }
}

extern "C" void kernel_launch(void* const* d_in, const int* in_sizes, int n_in,
                              void* d_out, int out_size, void* d_ws, size_t ws_size,
                              hipStream_t stream){
  (void)in_sizes; (void)n_in; (void)out_size; (void)ws_size;
  const float* mid  = (const float*)d_in[0];
  const float* occ  = (const float*)d_in[1];
  const float* prev = (const float*)d_in[2];
  const float* off1w= (const float*)d_in[3];
  const float* off1b= (const float*)d_in[4];
  const float* off2w= (const float*)d_in[5];
  const float* kvw  = (const float*)d_in[6];
  const float* kvb  = (const float*)d_in[7];
  const float* qw   = (const float*)d_in[8];
  const float* qb   = (const float*)d_in[9];
  const float* outw = (const float*)d_in[10];
  const float* outb = (const float*)d_in[11];
  const float* bng  = (const float*)d_in[12];
  const float* bnb  = (const float*)d_in[13];
  const float* bnm  = (const float*)d_in[14];
  const float* bnv  = (const float*)d_in[15];
  float* out = (float*)d_out;

  uint*   vols  = (uint*)d_ws;                          // 4*VV*16 uints   (16.8 MB)
  ushort* qbuf  = (ushort*)(vols + (size_t)4*VV*16);    // 2*64*VV ushort  (16.8 MB)
  uint*   o1pk  = (uint*)(qbuf + (size_t)2*CC*VV);      // 2*32*VV uint    (16.8 MB)
  ushort* offb  = (ushort*)(o1pk + (size_t)2*32*VV);    // 2*96*VV ushort  (25.2 MB)
  uint*   wA1   = (uint*)(offb + (size_t)2*96*VV);      // 55296
  uint*   wA2   = wA1 + 55296;                          // 82944
  uint*   wo    = wA2 + 82944;                          // 2048
  uint*   o0pk  = wo  + 2048;                           // 2*32*VV uint    (16.8 MB)

  fused_front<<<3620, 256, 0, stream>>>(occ, prev, mid, o0pk,
      off1w, wA1, off2w, wA2, outw, wo, kvw, kvb, qw, qb,
      (void*)vols, (void*)qbuf, out);
  conv3_mfma<64,1,1><<<512, 256, 0, stream>>>(o0pk, wA1, off1b, (void*)o1pk);
  conv3_mfma<96,0,0><<<512, 256, 0, stream>>>(o1pk, wA2, off1b, (void*)offb);
  sample_attn_kernel<<<8192, 256, 0, stream>>>(qbuf, offb, vols, wo,
      outb, bng, bnb, bnm, bnv, out);
}